// Round 5
// baseline (350.393 us; speedup 1.0000x reference)
//
#include <hip/hip_runtime.h>
#include <hip/hip_bf16.h>
#include <math.h>

// Problem: x[16384][512] f32, y[2048][5][512] f32 -> softmax(x @ mean_s(y).T) [16384][2048] f32
#define QTOT 16384
#define CDIM 2048
#define DDIM 512
#define SDIM 5

#define NKT   16                 // k-tiles of 32
#define NCTG  128                // c-tiles of 16
#define MB    32                 // rows per block
#define NT    512                // 8 waves
#define NWAVE 8

typedef short  s8v   __attribute__((ext_vector_type(8)));  // 8 bf16 (MFMA A/B frag)
typedef float  f32x4 __attribute__((ext_vector_type(4)));  // MFMA C/D frag

__device__ __forceinline__ unsigned short f2bf(float f) {
  unsigned int u = __float_as_uint(f);
  return (unsigned short)((u + 0x7FFFu + ((u >> 16) & 1u)) >> 16);
}
__device__ __forceinline__ float bf2f(unsigned short h) {
  return __uint_as_float(((unsigned int)h) << 16);
}
__device__ __forceinline__ void gload_lds16(const void* g, void* l) {
  __builtin_amdgcn_global_load_lds(
      (const __attribute__((address_space(1))) void*)g,
      (__attribute__((address_space(3))) void*)l, 16, 0, 0);
}

// ---------------------------------------------------------------------------
// Prep: P[c][k] = mean_s y[c][s][k]; split hi/lo bf16; fragment-major:
//   byte offset ((kt*128 + ctg)*2 + h)*1024 + lane*16 + j*2
//   (lane = (c&15) + 16*((k&31)>>3), j = k&7)
// => stage (kt, cg of 16 ctg) is a CONTIGUOUS 32KB block matching the LDS
//    layout exactly -> linear global_load_lds, no swizzle.
__global__ void __launch_bounds__(256)
prep_kernel(const float* __restrict__ y, unsigned short* __restrict__ bf) {
  const int t  = threadIdx.x;
  const int c0 = blockIdx.x * 8;           // 256 blocks x 8 classes
  #pragma unroll
  for (int e = 0; e < 16; ++e) {
    int flat = e * 256 + t;
    int cl   = flat >> 9;
    int k    = flat & 511;
    int c    = c0 + cl;
    const float* p = y + (size_t)c * (SDIM * DDIM) + k;
    float s = 0.f;
    #pragma unroll
    for (int ss = 0; ss < SDIM; ++ss) s += p[ss * DDIM];
    float v  = s * 0.2f;
    unsigned short hi = f2bf(v);
    unsigned short lo = f2bf(v - bf2f(hi));
    int kt   = k >> 5;
    int ctg  = c >> 4;
    int lane = (c & 15) + 16 * ((k & 31) >> 3);
    int j    = k & 7;
    size_t base = ((size_t)(kt * NCTG + ctg) * 2) * 512 + lane * 8 + j;
    bf[base]       = hi;
    bf[base + 512] = lo;
  }
}

// ---------------------------------------------------------------------------
#define MFMA(a, b, c) __builtin_amdgcn_mfma_f32_16x16x32_bf16(a, b, c, 0, 0, 0)

// Fused GEMM (3-pass bf16 MFMA) + row softmax.
// B staged through LDS via global_load_lds double-buffer (T3/T4 minimum
// 2-phase): 128 stages of 32KB = (kt, 256-col group). One barrier per stage,
// counted drain placed a full compute window after issue. MFMAs read LDS only.
// 8 waves: wave = (mt = w>>2: 16 rows, q = w&3: col quarter of each group).
__global__ void __launch_bounds__(NT, 2)
gemm_softmax_kernel(const float* __restrict__ x,
                    const unsigned short* __restrict__ bf,
                    float* __restrict__ out) {
  __shared__ unsigned short ldsA[32768];      // A frags [kt][mt][h][lane][8], 64KB
  __shared__ unsigned short ldsB[2][16384];   // 2 x 32KB B stage buffers

  const int t    = threadIdx.x;
  const int lane = t & 63;
  const int w    = t >> 6;                    // 0..7
  const int mt   = w >> 2;                    // row half (16 rows)
  const int q    = w & 3;                     // col quarter within stage group
  const int q0   = blockIdx.x * MB;
  const char* bfB = (const char*)bf;
  const int t16  = t * 16;

  // ---- issue B stage 0 (kt0, cg0) into buf0; latency hides under A staging ----
  {
    const char* src = bfB + t16;
    char* dst = (char*)&ldsB[0][0] + t16;
    gload_lds16(src,          dst);
    gload_lds16(src +  8192,  dst +  8192);
    gload_lds16(src + 16384,  dst + 16384);
    gload_lds16(src + 24576,  dst + 24576);
  }

  // ---- stage A: rows q0..q0+31 f32 coalesced -> hi/lo bf16 frag layout ----
  {
    const float4* x4 = (const float4*)(x + (size_t)q0 * DDIM);
    #pragma unroll
    for (int i = 0; i < 8; ++i) {
      int idx = t + NT * i;                   // 4096 float4 total
      int qq  = idx >> 7;
      int k4  = idx & 127;
      float4 f = x4[(size_t)qq * 128 + k4];
      int kt    = k4 >> 3;
      int mtt   = qq >> 4;
      int lanea = (qq & 15) + 16 * ((k4 >> 1) & 3);
      int j0    = (k4 & 1) * 4;
      unsigned short h0 = f2bf(f.x), h1 = f2bf(f.y), h2 = f2bf(f.z), h3 = f2bf(f.w);
      unsigned short l0 = f2bf(f.x - bf2f(h0)), l1 = f2bf(f.y - bf2f(h1));
      unsigned short l2 = f2bf(f.z - bf2f(h2)), l3 = f2bf(f.w - bf2f(h3));
      ushort4* dh = (ushort4*)&ldsA[((kt * 4 + mtt * 2 + 0) * 512) + lanea * 8 + j0];
      ushort4* dl = (ushort4*)&ldsA[((kt * 4 + mtt * 2 + 1) * 512) + lanea * 8 + j0];
      *dh = make_ushort4(h0, h1, h2, h3);
      *dl = make_ushort4(l0, l1, l2, l3);
    }
  }
  __syncthreads();   // drains vmcnt+lgkmcnt: A staged AND B stage0 landed

  f32x4 acc[8][4];   // [col-group][c-tile within quarter]
  #pragma unroll
  for (int cg = 0; cg < 8; ++cg)
    #pragma unroll
    for (int ci = 0; ci < 4; ++ci) acc[cg][ci] = (f32x4)0.f;

  const s8v* A8 = (const s8v*)ldsA;
  const int abase = mt * 128 + lane;                 // s8v units: mt*2*64
  const char* ldsBq = (const char*)&ldsB[0][0] + q * 8192 + lane * 16;

  #pragma unroll 1
  for (int kt = 0; kt < NKT; ++kt) {
    const int kb = kt * 256 + abase;                 // kt*4*64 s8v units
    s8v ah = A8[kb];                                 // this wave's mt, hi
    s8v al = A8[kb + 64];                            // lo
    #pragma unroll
    for (int cg = 0; cg < 8; ++cg) {
      // issue NEXT stage into the other buffer (drained a full stage later)
      {
        const int nkt = (cg == 7) ? ((kt + 1) & 15) : kt;   // wrap: dead load
        const int ncg = (cg + 1) & 7;
        const char* src = bfB + (size_t)nkt * 262144 + ncg * 32768 + t16;
        char* dst = (char*)&ldsB[(cg + 1) & 1][0] + t16;
        gload_lds16(src,          dst);
        gload_lds16(src +  8192,  dst +  8192);
        gload_lds16(src + 16384,  dst + 16384);
        gload_lds16(src + 24576,  dst + 24576);
      }
      // B frags from current buffer (lane-contiguous b128, conflict-free)
      const s8v* Bb = (const s8v*)(ldsBq + (cg & 1) * 32768);
      s8v b0h = Bb[0],   b1h = Bb[128], b2h = Bb[256], b3h = Bb[384];
      s8v b0l = Bb[64],  b1l = Bb[192], b2l = Bb[320], b3l = Bb[448];
      // 12 MFMA, dep distance 4 on each acc
      acc[cg][0] = MFMA(ah, b0h, acc[cg][0]);
      acc[cg][1] = MFMA(ah, b1h, acc[cg][1]);
      acc[cg][2] = MFMA(ah, b2h, acc[cg][2]);
      acc[cg][3] = MFMA(ah, b3h, acc[cg][3]);
      acc[cg][0] = MFMA(al, b0h, acc[cg][0]);
      acc[cg][1] = MFMA(al, b1h, acc[cg][1]);
      acc[cg][2] = MFMA(al, b2h, acc[cg][2]);
      acc[cg][3] = MFMA(al, b3h, acc[cg][3]);
      acc[cg][0] = MFMA(ah, b0l, acc[cg][0]);
      acc[cg][1] = MFMA(ah, b1l, acc[cg][1]);
      acc[cg][2] = MFMA(ah, b2l, acc[cg][2]);
      acc[cg][3] = MFMA(ah, b3l, acc[cg][3]);
      // next-stage data landed (issued ~466cy ago); sync buffer swap
      asm volatile("s_waitcnt vmcnt(0)" ::: "memory");
      __builtin_amdgcn_s_barrier();
      __builtin_amdgcn_sched_barrier(0);
    }
  }
  __syncthreads();   // fence before reusing ldsA for reductions

  // ------------------- softmax over c (rows q0..q0+31) ----------------------
  // C/D layout: col = lane&15, row = (lane>>4)*4 + reg. Wave's cols:
  // cg*256 + q*64 + ci*16 + cl; rows mt*16 + g*4 + r.
  float* red = (float*)ldsA;     // [row 0..31][q 0..3]: max at 0, sum at +128
  const int g  = lane >> 4;
  const int cl = lane & 15;

  float mx[4];
  #pragma unroll
  for (int r = 0; r < 4; ++r) {
    float v = acc[0][0][r];
    #pragma unroll
    for (int cg = 0; cg < 8; ++cg)
      #pragma unroll
      for (int ci = 0; ci < 4; ++ci)
        if (cg | ci) v = fmaxf(v, acc[cg][ci][r]);
    #pragma unroll
    for (int off = 1; off < 16; off <<= 1) v = fmaxf(v, __shfl_xor(v, off, 64));
    mx[r] = v;
  }
  if (cl == 0) {
    #pragma unroll
    for (int r = 0; r < 4; ++r) red[(mt * 16 + g * 4 + r) * 4 + q] = mx[r];
  }
  __syncthreads();
  #pragma unroll
  for (int r = 0; r < 4; ++r) {
    const float* rp = &red[(mt * 16 + g * 4 + r) * 4];
    mx[r] = fmaxf(fmaxf(rp[0], rp[1]), fmaxf(rp[2], rp[3]));
  }

  float sm[4];
  #pragma unroll
  for (int r = 0; r < 4; ++r) {
    float s = 0.f;
    #pragma unroll
    for (int cg = 0; cg < 8; ++cg)
      #pragma unroll
      for (int ci = 0; ci < 4; ++ci) {
        float e = __expf(acc[cg][ci][r] - mx[r]);
        acc[cg][ci][r] = e;
        s += e;
      }
    #pragma unroll
    for (int off = 1; off < 16; off <<= 1) s += __shfl_xor(s, off, 64);
    sm[r] = s;
  }
  if (cl == 0) {
    #pragma unroll
    for (int r = 0; r < 4; ++r) red[128 + (mt * 16 + g * 4 + r) * 4 + q] = sm[r];
  }
  __syncthreads();

  #pragma unroll
  for (int r = 0; r < 4; ++r) {
    const float* rp = &red[128 + (mt * 16 + g * 4 + r) * 4];
    float s = rp[0] + rp[1] + rp[2] + rp[3];
    float inv = 1.0f / s;
    float* orow = out + (size_t)(q0 + mt * 16 + g * 4 + r) * CDIM + q * 64 + cl;
    #pragma unroll
    for (int cg = 0; cg < 8; ++cg)
      #pragma unroll
      for (int ci = 0; ci < 4; ++ci)
        orow[cg * 256 + ci * 16] = acc[cg][ci][r] * inv;
  }
}

// ---------------------------------------------------------------------------
extern "C" void kernel_launch(void* const* d_in, const int* in_sizes, int n_in,
                              void* d_out, int out_size, void* d_ws, size_t ws_size,
                              hipStream_t stream) {
  const float* x = (const float*)d_in[0];          // [16384][512]
  const float* y = (const float*)d_in[1];          // [2048][5][512]
  float* out     = (float*)d_out;                  // [16384][2048]
  unsigned short* bf = (unsigned short*)d_ws;      // Bf frag-major, 4MB

  hipLaunchKernelGGL(prep_kernel, dim3(256), dim3(256), 0, stream, y, bf);
  hipLaunchKernelGGL(gemm_softmax_kernel, dim3(QTOT / MB), dim3(NT), 0, stream,
                     x, bf, out);
}